// Round 1
// baseline (136.097 us; speedup 1.0000x reference)
//
#include <hip/hip_runtime.h>
#include <math.h>

// fab_penalty_ls_curve: curvature penalty over mirrored level-set field.
// Strategy: compute only the left half (j in [0,W)) of the virtual [H, 2W]
// mirrored grid and double the sum (the mirrored half is an exact reflection:
// eps_y and eps_xy flip sign, but k uses eps_y^2 and eps_y*eps_xy only).
// One thread per column within a 256-wide tile; each thread walks 16
// consecutive rows for L1 stencil reuse. Double accumulation -> block
// partials in d_ws -> single-block finish kernel.

#define BLOCK_X 256
#define ROWS_PER 16

__global__ __launch_bounds__(BLOCK_X) void curve_partial_kernel(
    const float* __restrict__ eps, const float* __restrict__ gs,
    double* __restrict__ partial, int Hn, int Wn)
{
    const int tx = threadIdx.x;
    const int j  = blockIdx.x * BLOCK_X + tx;   // column in [0, Wn)
    const int i0 = blockIdx.y * ROWS_PER;

    const float d   = gs[0];
    const float rd  = 1.0f / d;
    const float rd2 = 0.5f * rd;
    const float SC  = 1e-12f;
    const float FLOORV = (float)(1e-32 / 6.0);
    const float pi_d = 3.14159265358979323846f / 1.1f;

    // column indices (fixed per thread); jp/jpp may cross the mirror seam
    const int jm  = (j > 0) ? j - 1 : 0;
    const int jmm = (j > 1) ? j - 2 : 0;
    const int jp  = j + 1;      // < 2*Wn always
    const int jpp = j + 2;
    const int cjp  = (jp  < Wn) ? jp  : (2 * Wn - 1 - jp);
    const int cjpp = (jpp < Wn) ? jpp : (2 * Wn - 1 - jpp);
    const float syj = (j == 0)  ? rd : rd2;
    const float sym = (jm == 0) ? rd : rd2;
    const float syp = rd2;      // jp is never a boundary of the 2W grid

    double acc = 0.0;
    for (int r = 0; r < ROWS_PER; ++r) {
        const int i   = i0 + r;
        const int im  = (i > 0) ? i - 1 : 0;
        const int ip  = (i < Hn - 1) ? i + 1 : Hn - 1;
        const int imm = (im > 0) ? im - 1 : 0;
        const int ipp = (ip < Hn - 1) ? ip + 1 : Hn - 1;
        const float sxi = (i == 0 || i == Hn - 1) ? rd : rd2;
        const float sxm = (im == 0) ? rd : rd2;
        const float sxp = (ip == Hn - 1) ? rd : rd2;

        const float* rowc  = eps + (size_t)i   * Wn;
        const float* rown  = eps + (size_t)im  * Wn;
        const float* rows_ = eps + (size_t)ip  * Wn;
        const float* rownn = eps + (size_t)imm * Wn;
        const float* rowss = eps + (size_t)ipp * Wn;

        const float e_c  = rowc[j];
        const float e_n  = rown[j],   e_s  = rows_[j];
        const float e_nn = rownn[j],  e_ss = rowss[j];
        const float e_w  = rowc[jm],  e_e  = rowc[cjp];
        const float e_ww = rowc[jmm], e_ee = rowc[cjpp];
        const float e_nw = rown[jm],  e_ne = rown[cjp];
        const float e_sw = rows_[jm], e_se = rows_[cjp];

        // first derivatives at (i,j)
        const float ex_c = (e_s - e_n) * sxi + SC;
        const float ey_c = (e_e - e_w) * syj + SC;

        // eps_x at rows im/ip (for eps_xx)
        float ex_n = (e_c - e_nn) * sxm + SC;
        if (i == 0) ex_n = ex_c;          // im == i at top boundary
        float ex_s = (e_ss - e_c) * sxp + SC;
        if (i == Hn - 1) ex_s = ex_c;     // ip == i at bottom boundary
        const float eps_xx = (ex_s - ex_n) * sxi;

        // eps_y at cols jm/jp (for eps_yy)
        float ey_w = (e_c - e_ww) * sym + SC;
        if (j == 0) ey_w = ey_c;          // jm == j at left boundary
        const float ey_e = (e_ee - e_c) * syp + SC;
        const float eps_yy = (ey_e - ey_w) * syj;

        // eps_xy = Dy(eps_x); the +SC cancels in the difference
        const float eps_xy = ((e_se - e_ne) - (e_sw - e_nw)) * sxi * syj;

        const float ev  = fmaxf(sqrtf(ex_c * ex_c + ey_c * ey_c), FLOORV);
        const float num = ex_c * ex_c * eps_yy
                        - 2.0f * ex_c * ey_c * eps_xy
                        + ey_c * ey_c * eps_xx;
        const float k   = num / (ev * ev * ev);
        const float cc  = fabsf(k * atanf(ev / e_c)) - pi_d;
        const float t   = (cc > 0.0f) ? cc : 0.0f;   // NaN -> 0 (nansum)
        acc += (double)t;
    }

    // block reduction: wave shuffle then LDS across 4 waves
    #pragma unroll
    for (int off = 32; off > 0; off >>= 1)
        acc += __shfl_down(acc, off, 64);
    __shared__ double lds[BLOCK_X / 64];
    const int lane = tx & 63, wv = tx >> 6;
    if (lane == 0) lds[wv] = acc;
    __syncthreads();
    if (tx == 0) {
        double s = 0.0;
        #pragma unroll
        for (int w = 0; w < BLOCK_X / 64; ++w) s += lds[w];
        partial[blockIdx.y * gridDim.x + blockIdx.x] = s;
    }
}

__global__ __launch_bounds__(256) void curve_finish_kernel(
    const double* __restrict__ partial, int n,
    const float* __restrict__ gs, float* __restrict__ out)
{
    const int tx = threadIdx.x;
    double acc = 0.0;
    for (int idx = tx; idx < n; idx += 256) acc += partial[idx];
    #pragma unroll
    for (int off = 32; off > 0; off >>= 1)
        acc += __shfl_down(acc, off, 64);
    __shared__ double lds[4];
    const int lane = tx & 63, wv = tx >> 6;
    if (lane == 0) lds[wv] = acc;
    __syncthreads();
    if (tx == 0) {
        const double d = (double)gs[0];
        // ×2 for the mirrored half; ×d² for the grid_size² factor (ALPHA=1)
        out[0] = (float)((lds[0] + lds[1] + lds[2] + lds[3]) * 2.0 * d * d);
    }
}

extern "C" void kernel_launch(void* const* d_in, const int* in_sizes, int n_in,
                              void* d_out, int out_size, void* d_ws, size_t ws_size,
                              hipStream_t stream) {
    const float* eps = (const float*)d_in[0];
    const float* gs  = (const float*)d_in[1];
    float* out = (float*)d_out;

    const int n = in_sizes[0];
    int Wn = (int)(sqrt((double)n) + 0.5);   // 4096 for 4096x4096
    int Hn = n / Wn;

    const int gx = (Wn + BLOCK_X - 1) / BLOCK_X;          // 16
    const int gy = (Hn + ROWS_PER - 1) / ROWS_PER;        // 256
    double* partial = (double*)d_ws;                      // gx*gy*8 B = 32 KiB

    curve_partial_kernel<<<dim3(gx, gy), BLOCK_X, 0, stream>>>(eps, gs, partial, Hn, Wn);
    curve_finish_kernel<<<1, 256, 0, stream>>>(partial, gx * gy, gs, out);
}